// Round 14
// baseline (137.153 us; speedup 1.0000x reference)
//
#include <hip/hip_runtime.h>
#include <cstdint>

typedef unsigned long long u64;
typedef unsigned int u32;

#define NB 4096
#define NW 64            // 64-bit words per mask row
#define MM 20
#define HH 16
#define COND_THRES 0.2f
#define IOU_THRES 0.3f
#define PI_F  3.14159265358979323846f
#define PI4_F 0.78539816339744830962f

// ---- workspace layout (bytes) ----
#define WS_KEPT    0                           // u64[64] kept bitmask
#define WS_VALID   512                         // u64[64] valid bitmask
#define WS_MASK    32768                       // u64[NB*NW] = 2 MiB
#define WS_BOX9S   (WS_MASK + NB*NW*8)         // float[NB*9]
#define WS_BEVS    (WS_BOX9S + NB*9*4)         // float4[NB]
#define WS_SCORES  (WS_BEVS + NB*16)           // float[NB]
#define WS_LABELS  (WS_SCORES + NB*4)          // int[NB]
#define WS_NBRW    (WS_LABELS + NB*4)          // u64[NB]

__device__ __forceinline__ u64 sort_key(float s, int i) {
  u32 sb = (s > COND_THRES) ? __float_as_uint(s) : 0u;
  return ((u64)(sb ^ 0xFFFFFFFFu) << 12) | (u64)i;
}

// ---------- K1: fused counting-rank + scatter + BEV. 256 blocks; 16 threads
// per box i count 256 j-keys each from LDS tiles (conflict-free: t=q*16+sub),
// shuffle-reduced; lane sub==0 scatters to sorted position. Also zeroes nbrw.
__global__ void __launch_bounds__(256) k_sort(const float* __restrict__ scores,
                                              const float* __restrict__ boxes9,
                                              const int* __restrict__ labels,
                                              float* __restrict__ box9s, float4* __restrict__ bevs,
                                              float* __restrict__ scoress, int* __restrict__ labelss,
                                              u64* __restrict__ nbrw) {
  #pragma clang fp contract(off)
  __shared__ u64 kj[256];
  int tid = threadIdx.x;
  int il = tid >> 4;          // local box 0..15
  int sub = tid & 15;         // 16 counters per box
  int i = blockIdx.x * 16 + il;
  if (blockIdx.x * 256 + tid < NB) nbrw[blockIdx.x * 256 + tid] = 0;  // only blocks <16 hit
  if (blockIdx.x < 16) nbrw[blockIdx.x * 256 + tid] = 0;
  u64 ki = sort_key(scores[i], i);
  int cnt = 0;
  for (int tile = 0; tile < 16; ++tile) {
    __syncthreads();
    int j = tile * 256 + tid;
    kj[tid] = sort_key(scores[j], j);
    __syncthreads();
    #pragma unroll
    for (int q = 0; q < 16; ++q)
      cnt += (kj[q * 16 + sub] < ki) ? 1 : 0;   // banks 2*sub: conflict-free
  }
  #pragma unroll
  for (int off = 8; off >= 1; off >>= 1)
    cnt += __shfl_down(cnt, off, 16);
  if (sub == 0) {
    int r = cnt;
    float b[9];
    #pragma unroll
    for (int f = 0; f < 9; ++f) b[f] = boxes9[i * 9 + f];
    #pragma unroll
    for (int f = 0; f < 9; ++f) box9s[r * 9 + f] = b[f];
    float ang = b[6] - floorf(b[6] / PI_F + 0.5f) * PI_F;
    bool sw = fabsf(ang) >= PI4_F;
    float dx = sw ? b[4] : b[3];
    float dy = sw ? b[3] : b[4];
    bevs[r] = make_float4(b[0] - dx * 0.5f, b[1] - dy * 0.5f,
                          b[0] + dx * 0.5f, b[1] + dy * 0.5f);
    scoress[r] = scores[i];
    labelss[r] = labels[i];
  }
}

// ---------- K2: pairwise over-matrix (symmetric), bit-packed rows.
// Fused nbrw update: word jt of row i holds an earlier valid neighbor =>
// atomicOr bit jt into nbrw[i] (rare; avg ~0.5 set words per box).
__global__ void __launch_bounds__(64) k_mask(const float4* __restrict__ bevs,
                                             const int* __restrict__ labelss,
                                             const float* __restrict__ scoress,
                                             u64* __restrict__ mask,
                                             u64* __restrict__ nbrw) {
  #pragma clang fp contract(off)
  __shared__ float4 bj[64];
  __shared__ int lj[64];
  int t = threadIdx.x;
  int jt = blockIdx.x;
  int it = blockIdx.y;
  int j = jt * 64 + t;
  bj[t] = bevs[j];
  lj[t] = labelss[j];
  u64 vj = __ballot(scoress[j] > COND_THRES);   // valid mask of this j-tile
  int i = it * 64 + t;
  float4 a = bevs[i];
  int la = labelss[i];
  float area_a = (a.z - a.x) * (a.w - a.y);
  __syncthreads();
  u64 w = 0;
  #pragma unroll 8
  for (int kk = 0; kk < 64; ++kk) {
    float4 bb = bj[kk];
    float xmin = fmaxf(a.x, bb.x), ymin = fmaxf(a.y, bb.y);
    float xmax = fminf(a.z, bb.z), ymax = fminf(a.w, bb.w);
    float inter = fmaxf(xmax - xmin, 0.0f) * fmaxf(ymax - ymin, 0.0f);
    float area_b = (bb.z - bb.x) * (bb.w - bb.y);
    float iou = inter / fmaxf(area_a + area_b - inter, 1e-6f);
    if ((iou > IOU_THRES) && (la == lj[kk])) w |= (1ull << kk);
  }
  mask[(u64)i * NW + jt] = w;
  if (jt <= it) {
    u64 below = (jt < it) ? ~0ull : ((1ull << t) - 1ull);
    if (w & vj & below) atomicOr(&nbrw[i], 1ull << jt);
  }
}

// ---------- K3: greedy NMS fixpoint; neighbor words register-cached so rounds
// are pure LDS/VALU. Also exports the valid bitmask for k_merge.
__global__ void __launch_bounds__(1024) k_nms(const u64* __restrict__ mask,
                                              const u64* __restrict__ nbrw,
                                              const float* __restrict__ scoress,
                                              u64* __restrict__ keptOut,
                                              u64* __restrict__ validOut) {
  __shared__ u64 decided[64], kept[64];
  __shared__ int remaining;
  int tid = threadIdx.x;
  if (tid < 64) {
    u64 v = 0;
    #pragma unroll 8
    for (int b = 0; b < 64; ++b)
      if (scoress[(tid << 6) | b] > COND_THRES) v |= (1ull << b);
    decided[tid] = ~v;       // invalid boxes decided (kept=0) from the start
    kept[tid] = 0;
    validOut[tid] = v;
  }
  if (tid == 0) remaining = 0;
  __syncthreads();
  if (tid < 64) atomicAdd(&remaining, __popcll(~decided[tid]));
  // register cache: up to 2 masked neighbor words per owned box
  u64 cw0[4], cw1[4];
  u32 meta[4];   // [5:0] idx0, [11:6] idx1, [13:12] n(min 2), [14] overflow
  #pragma unroll
  for (int s = 0; s < 4; ++s) {
    int i = tid + (s << 10);
    int wi = i >> 6;
    u64 bit = 1ull << (i & 63);
    u64 t = nbrw[i];
    int n = 0; u32 ovf = 0;
    u64 c0 = 0, c1 = 0; u32 i0 = 0, i1 = 0;
    while (t) {
      int w = __builtin_ctzll(t);
      t &= t - 1;
      u64 below = (w < wi) ? ~0ull : (bit - 1ull);
      u64 m = mask[(u64)i * NW + w] & below;
      if (n == 0)      { c0 = m; i0 = (u32)w; }
      else if (n == 1) { c1 = m; i1 = (u32)w; }
      else ovf = 1;
      ++n;
    }
    cw0[s] = c0; cw1[s] = c1;
    meta[s] = i0 | (i1 << 6) | ((u32)(n > 2 ? 2 : n) << 12) | (ovf << 14);
  }
  __syncthreads();
  while (remaining > 0) {
    int decIdx[4]; bool decKept[4]; int nDec = 0;
    #pragma unroll
    for (int s = 0; s < 4; ++s) {
      int i = tid + (s << 10);
      int wi = i >> 6;
      u64 bit = 1ull << (i & 63);
      if (decided[wi] & bit) continue;
      bool hasU = false, hasK = false;
      u32 mt = meta[s];
      if (!(mt & (1u << 14))) {
        int n = (mt >> 12) & 3;
        if (n >= 1) {
          int w = mt & 63;
          hasU = hasU || ((cw0[s] & ~decided[w]) != 0ull);
          hasK = hasK || ((cw0[s] & kept[w]) != 0ull);
        }
        if (n >= 2) {
          int w = (mt >> 6) & 63;
          hasU = hasU || ((cw1[s] & ~decided[w]) != 0ull);
          hasK = hasK || ((cw1[s] & kept[w]) != 0ull);
        }
      } else {
        u64 t = nbrw[i];
        while (t) {
          int w = __builtin_ctzll(t);
          t &= t - 1;
          u64 below = (w < wi) ? ~0ull : (bit - 1ull);
          u64 m = mask[(u64)i * NW + w] & below;
          hasU = hasU || ((m & ~decided[w]) != 0ull);
          hasK = hasK || ((m & kept[w]) != 0ull);
        }
      }
      if (!hasU) { decIdx[nDec] = i; decKept[nDec] = !hasK; ++nDec; }
    }
    __syncthreads();
    for (int d = 0; d < nDec; ++d) {
      int i = decIdx[d];
      u64 bit = 1ull << (i & 63);
      atomicOr(&decided[i >> 6], bit);
      if (decKept[d]) atomicOr(&kept[i >> 6], bit);
      atomicSub(&remaining, 1);
    }
    __syncthreads();
  }
  if (tid < 64) keptOut[tid] = kept[tid];
}

// ---------- K4: per-box merge + all outputs. One 64-thread block per sorted box.
// supstep fused inline: active <=> kept-bit(i); candidate j included <=>
// valid(j) && no kept k<i with over(k,j) (scan mask[j] & Kept below i).
__global__ void __launch_bounds__(64) k_merge(
    const u64* __restrict__ mask, const u64* __restrict__ keptIn,
    const u64* __restrict__ validIn,
    const float* __restrict__ box9s, const float* __restrict__ scoress,
    const int* __restrict__ labelss,
    const float* __restrict__ w1, const float* __restrict__ b1,
    const float* __restrict__ w2, const float* __restrict__ b2,
    const float* __restrict__ w3, const float* __restrict__ b3,
    float* __restrict__ out) {
  #pragma clang fp contract(off)
  __shared__ u64 Ksh[64];
  __shared__ int candList[MM];
  __shared__ float ob[MM][7];
  __shared__ float h1[7][HH];
  __shared__ float h2[7][HH];
  __shared__ float res[7];
  int i = blockIdx.x;
  int t = threadIdx.x;
  Ksh[t] = keptIn[t];
  u64 vw = validIn[t];
  __syncthreads();
  const int wi = i >> 6;
  bool active = ((Ksh[wi] >> (i & 63)) & 1ull) != 0ull;
  u64 wq = 0;
  int cnt = 0;
  if (active) {
    u64 w = mask[(u64)i * NW + t] & vw;           // valid candidates only
    const u64 topmask = (1ull << (i & 63)) - 1ull;
    while (w) {
      int b = __builtin_ctzll(w);
      w &= w - 1;
      int j = (t << 6) | b;
      bool sb = false;                            // suppressed before step i?
      for (int w2 = 0; w2 <= wi; ++w2) {
        u64 kk = Ksh[w2];
        if (w2 == wi) kk &= topmask;
        sb = sb || ((mask[(u64)j * NW + w2] & kk) != 0ull);
      }
      if (!sb) { wq |= (1ull << b); cnt++; }
    }
  }
  int incl = cnt;
  #pragma unroll
  for (int off = 1; off < 64; off <<= 1) {
    int v = __shfl_up(incl, off);
    if (t >= off) incl += v;
  }
  int excl = incl - cnt;
  int count = __shfl(incl, 63);
  bool merged = active && (count > 1);
  if (merged && wq) {
    int pos = excl;
    u64 ww = wq;
    while (ww && pos < MM) {
      int b = __builtin_ctzll(ww);
      ww &= ww - 1;
      candList[pos++] = (t << 6) | b;
    }
  }
  __syncthreads();
  if (merged) {
    int nc = count < MM ? count : MM;
    if (t < MM) {
      if (t < nc) {
        int j = candList[t];
        #pragma unroll
        for (int f = 0; f < 7; ++f) ob[t][f] = box9s[j * 9 + f];
      } else {
        #pragma unroll
        for (int f = 0; f < 7; ++f) ob[t][f] = 0.0f;
      }
    }
    __syncthreads();
    for (int o = t; o < 7 * HH; o += 64) {
      int f = o >> 4, hh = o & 15;
      float acc = b1[hh];
      #pragma unroll
      for (int m = 0; m < MM; ++m) acc += ob[m][f] * w1[m * HH + hh];
      h1[f][hh] = fmaxf(acc, 0.0f);
    }
    __syncthreads();
    for (int o = t; o < 7 * HH; o += 64) {
      int f = o >> 4, oo = o & 15;
      float acc = b2[oo];
      #pragma unroll
      for (int k = 0; k < HH; ++k) acc += h1[f][k] * w2[k * HH + oo];
      h2[f][oo] = fmaxf(acc, 0.0f);
    }
    __syncthreads();
    if (t < 7) {
      float acc = b3[0];
      #pragma unroll
      for (int k = 0; k < HH; ++k) acc += h2[t][k] * w3[k];
      if (t >= 3 && t < 6) acc = fmaxf(acc, 1e-5f);
      res[t] = acc;
    }
    __syncthreads();
  }
  if (t < 9) {
    float v = box9s[i * 9 + t];
    if (merged && t < 7) v = res[t];
    out[i * 9 + t] = v;
  }
  if (t == 0) {
    out[NB * 9 + i]          = scoress[i];
    out[NB * 9 + NB + i]     = (float)labelss[i];
    out[NB * 9 + 2 * NB + i] = active ? 1.0f : 0.0f;
  }
}

extern "C" void kernel_launch(void* const* d_in, const int* in_sizes, int n_in,
                              void* d_out, int out_size, void* d_ws, size_t ws_size,
                              hipStream_t stream) {
  const float* boxes9 = (const float*)d_in[0];
  const float* scores = (const float*)d_in[1];
  const int*   labels = (const int*)d_in[2];
  const float* w1 = (const float*)d_in[3];
  const float* b1 = (const float*)d_in[4];
  const float* w2 = (const float*)d_in[5];
  const float* b2 = (const float*)d_in[6];
  const float* w3 = (const float*)d_in[7];
  const float* b3 = (const float*)d_in[8];
  char* ws = (char*)d_ws;
  u64*    kept    = (u64*)(ws + WS_KEPT);
  u64*    valid   = (u64*)(ws + WS_VALID);
  u64*    mask    = (u64*)(ws + WS_MASK);
  float*  box9s   = (float*)(ws + WS_BOX9S);
  float4* bevs    = (float4*)(ws + WS_BEVS);
  float*  scoress = (float*)(ws + WS_SCORES);
  int*    labelss = (int*)(ws + WS_LABELS);
  u64*    nbrw    = (u64*)(ws + WS_NBRW);
  float*  out     = (float*)d_out;

  hipLaunchKernelGGL(k_sort,  dim3(NB / 16), dim3(256),  0, stream, scores, boxes9, labels,
                     box9s, bevs, scoress, labelss, nbrw);
  hipLaunchKernelGGL(k_mask,  dim3(64, 64),  dim3(64),   0, stream, bevs, labelss, scoress,
                     mask, nbrw);
  hipLaunchKernelGGL(k_nms,   dim3(1),       dim3(1024), 0, stream, mask, nbrw, scoress,
                     kept, valid);
  hipLaunchKernelGGL(k_merge, dim3(NB),      dim3(64),   0, stream, mask, kept, valid,
                     box9s, scoress, labelss, w1, b1, w2, b2, w3, b3, out);
}

// Round 15
// 136.524 us; speedup vs baseline: 1.0046x; 1.0046x over previous
//
#include <hip/hip_runtime.h>
#include <cstdint>

typedef unsigned long long u64;
typedef unsigned int u32;

#define NB 4096
#define NW 64            // 64-bit words per mask row
#define MM 20
#define HH 16
#define COND_THRES 0.2f
#define IOU_THRES 0.3f
#define PI_F  3.14159265358979323846f
#define PI4_F 0.78539816339744830962f

// ---- workspace layout (bytes) ----
#define WS_KEPT    0                           // u64[64] kept bitmask
#define WS_MASK    32768                       // u64[NB*NW] = 2 MiB
#define WS_BOX9S   (WS_MASK + NB*NW*8)         // float[NB*9]
#define WS_BEVS    (WS_BOX9S + NB*9*4)         // float4[NB]
#define WS_SCORES  (WS_BEVS + NB*16)           // float[NB]
#define WS_LABELS  (WS_SCORES + NB*4)          // int[NB]
#define WS_SUPSTEP (WS_LABELS + NB*4)          // int[NB]
#define WS_NBRW    (WS_SUPSTEP + NB*4)         // u64[NB]

__device__ __forceinline__ u64 sort_key(float s, int i) {
  u32 sb = (s > COND_THRES) ? __float_as_uint(s) : 0u;
  return ((u64)(sb ^ 0xFFFFFFFFu) << 12) | (u64)i;
}

// ---------- K1: fused counting-rank + scatter + BEV. 256 blocks; 16 threads
// per box i count 256 j-keys each from LDS tiles (conflict-free: t=q*16+sub),
// shuffle-reduced; lane sub==0 scatters to sorted position. Also zeroes nbrw.
__global__ void __launch_bounds__(256) k_sort(const float* __restrict__ scores,
                                              const float* __restrict__ boxes9,
                                              const int* __restrict__ labels,
                                              float* __restrict__ box9s, float4* __restrict__ bevs,
                                              float* __restrict__ scoress, int* __restrict__ labelss,
                                              u64* __restrict__ nbrw) {
  #pragma clang fp contract(off)
  __shared__ u64 kj[256];
  int tid = threadIdx.x;
  int il = tid >> 4;          // local box 0..15
  int sub = tid & 15;         // 16 counters per box
  int i = blockIdx.x * 16 + il;
  if (blockIdx.x < 16) nbrw[blockIdx.x * 256 + tid] = 0;
  u64 ki = sort_key(scores[i], i);
  int cnt = 0;
  for (int tile = 0; tile < 16; ++tile) {
    __syncthreads();
    int j = tile * 256 + tid;
    kj[tid] = sort_key(scores[j], j);
    __syncthreads();
    #pragma unroll
    for (int q = 0; q < 16; ++q)
      cnt += (kj[q * 16 + sub] < ki) ? 1 : 0;   // banks 2*sub: conflict-free
  }
  #pragma unroll
  for (int off = 8; off >= 1; off >>= 1)
    cnt += __shfl_down(cnt, off, 16);
  if (sub == 0) {
    int r = cnt;
    float b[9];
    #pragma unroll
    for (int f = 0; f < 9; ++f) b[f] = boxes9[i * 9 + f];
    #pragma unroll
    for (int f = 0; f < 9; ++f) box9s[r * 9 + f] = b[f];
    float ang = b[6] - floorf(b[6] / PI_F + 0.5f) * PI_F;
    bool sw = fabsf(ang) >= PI4_F;
    float dx = sw ? b[4] : b[3];
    float dy = sw ? b[3] : b[4];
    bevs[r] = make_float4(b[0] - dx * 0.5f, b[1] - dy * 0.5f,
                          b[0] + dx * 0.5f, b[1] + dy * 0.5f);
    scoress[r] = scores[i];
    labelss[r] = labels[i];
  }
}

// ---------- K2: pairwise over-matrix (symmetric), bit-packed rows.
// Fused nbrw update: word jt of row i holds an earlier valid neighbor =>
// atomicOr bit jt into nbrw[i] (rare; avg ~0.5 set words per box).
__global__ void __launch_bounds__(64) k_mask(const float4* __restrict__ bevs,
                                             const int* __restrict__ labelss,
                                             const float* __restrict__ scoress,
                                             u64* __restrict__ mask,
                                             u64* __restrict__ nbrw) {
  #pragma clang fp contract(off)
  __shared__ float4 bj[64];
  __shared__ int lj[64];
  int t = threadIdx.x;
  int jt = blockIdx.x;
  int it = blockIdx.y;
  int j = jt * 64 + t;
  bj[t] = bevs[j];
  lj[t] = labelss[j];
  u64 vj = __ballot(scoress[j] > COND_THRES);   // valid mask of this j-tile
  int i = it * 64 + t;
  float4 a = bevs[i];
  int la = labelss[i];
  float area_a = (a.z - a.x) * (a.w - a.y);
  __syncthreads();
  u64 w = 0;
  #pragma unroll 8
  for (int kk = 0; kk < 64; ++kk) {
    float4 bb = bj[kk];
    float xmin = fmaxf(a.x, bb.x), ymin = fmaxf(a.y, bb.y);
    float xmax = fminf(a.z, bb.z), ymax = fminf(a.w, bb.w);
    float inter = fmaxf(xmax - xmin, 0.0f) * fmaxf(ymax - ymin, 0.0f);
    float area_b = (bb.z - bb.x) * (bb.w - bb.y);
    float iou = inter / fmaxf(area_a + area_b - inter, 1e-6f);
    if ((iou > IOU_THRES) && (la == lj[kk])) w |= (1ull << kk);
  }
  mask[(u64)i * NW + jt] = w;
  if (jt <= it) {
    u64 below = (jt < it) ? ~0ull : ((1ull << t) - 1ull);
    if (w & vj & below) atomicOr(&nbrw[i], 1ull << jt);
  }
}

// ---------- K3: greedy NMS fixpoint; neighbor words register-cached so rounds
// are pure LDS/VALU (global mask touched only in init + rare >2-word fallback).
__global__ void __launch_bounds__(1024) k_nms(const u64* __restrict__ mask,
                                              const u64* __restrict__ nbrw,
                                              const float* __restrict__ scoress,
                                              u64* __restrict__ keptOut) {
  __shared__ u64 decided[64], kept[64];
  __shared__ int remaining;
  int tid = threadIdx.x;
  if (tid < 64) {
    u64 v = 0;
    #pragma unroll 8
    for (int b = 0; b < 64; ++b)
      if (scoress[(tid << 6) | b] > COND_THRES) v |= (1ull << b);
    decided[tid] = ~v;       // invalid boxes decided (kept=0) from the start
    kept[tid] = 0;
  }
  if (tid == 0) remaining = 0;
  __syncthreads();
  if (tid < 64) atomicAdd(&remaining, __popcll(~decided[tid]));
  // register cache: up to 2 masked neighbor words per owned box
  u64 cw0[4], cw1[4];
  u32 meta[4];   // [5:0] idx0, [11:6] idx1, [13:12] n(min 2), [14] overflow
  #pragma unroll
  for (int s = 0; s < 4; ++s) {
    int i = tid + (s << 10);
    int wi = i >> 6;
    u64 bit = 1ull << (i & 63);
    u64 t = nbrw[i];
    int n = 0; u32 ovf = 0;
    u64 c0 = 0, c1 = 0; u32 i0 = 0, i1 = 0;
    while (t) {
      int w = __builtin_ctzll(t);
      t &= t - 1;
      u64 below = (w < wi) ? ~0ull : (bit - 1ull);
      u64 m = mask[(u64)i * NW + w] & below;
      if (n == 0)      { c0 = m; i0 = (u32)w; }
      else if (n == 1) { c1 = m; i1 = (u32)w; }
      else ovf = 1;
      ++n;
    }
    cw0[s] = c0; cw1[s] = c1;
    meta[s] = i0 | (i1 << 6) | ((u32)(n > 2 ? 2 : n) << 12) | (ovf << 14);
  }
  __syncthreads();
  while (remaining > 0) {
    int decIdx[4]; bool decKept[4]; int nDec = 0;
    #pragma unroll
    for (int s = 0; s < 4; ++s) {
      int i = tid + (s << 10);
      int wi = i >> 6;
      u64 bit = 1ull << (i & 63);
      if (decided[wi] & bit) continue;
      bool hasU = false, hasK = false;
      u32 mt = meta[s];
      if (!(mt & (1u << 14))) {
        int n = (mt >> 12) & 3;
        if (n >= 1) {
          int w = mt & 63;
          hasU = hasU || ((cw0[s] & ~decided[w]) != 0ull);
          hasK = hasK || ((cw0[s] & kept[w]) != 0ull);
        }
        if (n >= 2) {
          int w = (mt >> 6) & 63;
          hasU = hasU || ((cw1[s] & ~decided[w]) != 0ull);
          hasK = hasK || ((cw1[s] & kept[w]) != 0ull);
        }
      } else {
        u64 t = nbrw[i];
        while (t) {
          int w = __builtin_ctzll(t);
          t &= t - 1;
          u64 below = (w < wi) ? ~0ull : (bit - 1ull);
          u64 m = mask[(u64)i * NW + w] & below;
          hasU = hasU || ((m & ~decided[w]) != 0ull);
          hasK = hasK || ((m & kept[w]) != 0ull);
        }
      }
      if (!hasU) { decIdx[nDec] = i; decKept[nDec] = !hasK; ++nDec; }
    }
    __syncthreads();
    for (int d = 0; d < nDec; ++d) {
      int i = decIdx[d];
      u64 bit = 1ull << (i & 63);
      atomicOr(&decided[i >> 6], bit);
      if (decKept[d]) atomicOr(&kept[i >> 6], bit);
      atomicSub(&remaining, 1);
    }
    __syncthreads();
  }
  if (tid < 64) keptOut[tid] = kept[tid];
}

// ---------- K4: supstep[j] = min{i kept : over(i,j)} (parallel), -1 if invalid.
__global__ void __launch_bounds__(256) k_supstep(const u64* __restrict__ mask,
                                                 const u64* __restrict__ kept,
                                                 const float* __restrict__ scoress,
                                                 int* __restrict__ supstep) {
  __shared__ u64 K[64];
  if (threadIdx.x < 64) K[threadIdx.x] = kept[threadIdx.x];
  __syncthreads();
  int j = blockIdx.x * 256 + threadIdx.x;
  if (!(scoress[j] > COND_THRES)) { supstep[j] = -1; return; }
  int res = 0x7FFFFFFF;
  #pragma unroll 4
  for (int w = 0; w < 64; ++w) {
    u64 m = mask[(u64)j * NW + w] & K[w];
    if (m) { res = (w << 6) + __builtin_ctzll(m); break; }
  }
  supstep[j] = res;
}

// ---------- K5: per-box merge + all outputs. One 64-thread block per sorted box.
__global__ void __launch_bounds__(64) k_merge(
    const u64* __restrict__ mask, const int* __restrict__ supstep,
    const float* __restrict__ box9s, const float* __restrict__ scoress,
    const int* __restrict__ labelss,
    const float* __restrict__ w1, const float* __restrict__ b1,
    const float* __restrict__ w2, const float* __restrict__ b2,
    const float* __restrict__ w3, const float* __restrict__ b3,
    float* __restrict__ out) {
  #pragma clang fp contract(off)
  __shared__ int candList[MM];
  __shared__ float ob[MM][7];
  __shared__ float h1[7][HH];
  __shared__ float h2[7][HH];
  __shared__ float res[7];
  int i = blockIdx.x;
  int t = threadIdx.x;
  bool active = (supstep[i] == i);
  u64 wq = 0;
  int cnt = 0;
  if (active) {
    u64 w = mask[(u64)i * NW + t];
    while (w) {
      int b = __builtin_ctzll(w);
      w &= w - 1;
      int j = (t << 6) | b;
      if (supstep[j] >= i) { wq |= (1ull << b); cnt++; }
    }
  }
  int incl = cnt;
  #pragma unroll
  for (int off = 1; off < 64; off <<= 1) {
    int v = __shfl_up(incl, off);
    if (t >= off) incl += v;
  }
  int excl = incl - cnt;
  int count = __shfl(incl, 63);
  bool merged = active && (count > 1);
  if (merged && wq) {
    int pos = excl;
    u64 ww = wq;
    while (ww && pos < MM) {
      int b = __builtin_ctzll(ww);
      ww &= ww - 1;
      candList[pos++] = (t << 6) | b;
    }
  }
  __syncthreads();
  if (merged) {
    int nc = count < MM ? count : MM;
    if (t < MM) {
      if (t < nc) {
        int j = candList[t];
        #pragma unroll
        for (int f = 0; f < 7; ++f) ob[t][f] = box9s[j * 9 + f];
      } else {
        #pragma unroll
        for (int f = 0; f < 7; ++f) ob[t][f] = 0.0f;
      }
    }
    __syncthreads();
    for (int o = t; o < 7 * HH; o += 64) {
      int f = o >> 4, hh = o & 15;
      float acc = b1[hh];
      #pragma unroll
      for (int m = 0; m < MM; ++m) acc += ob[m][f] * w1[m * HH + hh];
      h1[f][hh] = fmaxf(acc, 0.0f);
    }
    __syncthreads();
    for (int o = t; o < 7 * HH; o += 64) {
      int f = o >> 4, oo = o & 15;
      float acc = b2[oo];
      #pragma unroll
      for (int k = 0; k < HH; ++k) acc += h1[f][k] * w2[k * HH + oo];
      h2[f][oo] = fmaxf(acc, 0.0f);
    }
    __syncthreads();
    if (t < 7) {
      float acc = b3[0];
      #pragma unroll
      for (int k = 0; k < HH; ++k) acc += h2[t][k] * w3[k];
      if (t >= 3 && t < 6) acc = fmaxf(acc, 1e-5f);
      res[t] = acc;
    }
    __syncthreads();
  }
  if (t < 9) {
    float v = box9s[i * 9 + t];
    if (merged && t < 7) v = res[t];
    out[i * 9 + t] = v;
  }
  if (t == 0) {
    out[NB * 9 + i]          = scoress[i];
    out[NB * 9 + NB + i]     = (float)labelss[i];
    out[NB * 9 + 2 * NB + i] = active ? 1.0f : 0.0f;
  }
}

extern "C" void kernel_launch(void* const* d_in, const int* in_sizes, int n_in,
                              void* d_out, int out_size, void* d_ws, size_t ws_size,
                              hipStream_t stream) {
  const float* boxes9 = (const float*)d_in[0];
  const float* scores = (const float*)d_in[1];
  const int*   labels = (const int*)d_in[2];
  const float* w1 = (const float*)d_in[3];
  const float* b1 = (const float*)d_in[4];
  const float* w2 = (const float*)d_in[5];
  const float* b2 = (const float*)d_in[6];
  const float* w3 = (const float*)d_in[7];
  const float* b3 = (const float*)d_in[8];
  char* ws = (char*)d_ws;
  u64*    kept    = (u64*)(ws + WS_KEPT);
  u64*    mask    = (u64*)(ws + WS_MASK);
  float*  box9s   = (float*)(ws + WS_BOX9S);
  float4* bevs    = (float4*)(ws + WS_BEVS);
  float*  scoress = (float*)(ws + WS_SCORES);
  int*    labelss = (int*)(ws + WS_LABELS);
  int*    supstep = (int*)(ws + WS_SUPSTEP);
  u64*    nbrw    = (u64*)(ws + WS_NBRW);
  float*  out     = (float*)d_out;

  hipLaunchKernelGGL(k_sort,    dim3(NB / 16),  dim3(256),  0, stream, scores, boxes9, labels,
                     box9s, bevs, scoress, labelss, nbrw);
  hipLaunchKernelGGL(k_mask,    dim3(64, 64),   dim3(64),   0, stream, bevs, labelss, scoress,
                     mask, nbrw);
  hipLaunchKernelGGL(k_nms,     dim3(1),        dim3(1024), 0, stream, mask, nbrw, scoress, kept);
  hipLaunchKernelGGL(k_supstep, dim3(NB / 256), dim3(256),  0, stream, mask, kept, scoress, supstep);
  hipLaunchKernelGGL(k_merge,   dim3(NB),       dim3(64),   0, stream, mask, supstep,
                     box9s, scoress, labelss, w1, b1, w2, b2, w3, b3, out);
}

// Round 16
// 132.533 us; speedup vs baseline: 1.0349x; 1.0301x over previous
//
#include <hip/hip_runtime.h>
#include <cstdint>

typedef unsigned long long u64;
typedef unsigned int u32;

#define NB 4096
#define NW 64            // 64-bit words per mask row
#define MM 20
#define HH 16
#define COND_THRES 0.2f
#define IOU_THRES 0.3f
#define PI_F  3.14159265358979323846f
#define PI4_F 0.78539816339744830962f

// ---- workspace layout (bytes) ----
#define WS_KEPT    0                           // u64[64] kept bitmask
#define WS_MASK    32768                       // u64[NB*NW] = 2 MiB
#define WS_BOX9S   (WS_MASK + NB*NW*8)         // float[NB*9]
#define WS_BEVS    (WS_BOX9S + NB*9*4)         // float4[NB]
#define WS_SCORES  (WS_BEVS + NB*16)           // float[NB]
#define WS_LABELS  (WS_SCORES + NB*4)          // int[NB]
#define WS_SUPSTEP (WS_LABELS + NB*4)          // int[NB]
#define WS_NBRW    (WS_SUPSTEP + NB*4)         // u64[NB]
#define WS_PART    (WS_NBRW + NB*8)            // u32[NB*16] rank partials

__device__ __forceinline__ u64 sort_key(float s, int i) {
  u32 sb = (s > COND_THRES) ? __float_as_uint(s) : 0u;
  return ((u64)(sb ^ 0xFFFFFFFFu) << 12) | (u64)i;
}

// ---------- K1a: partial counting-rank (private partial per (i,jc), no atomics).
// Also zero-inits nbrw (written later by k_mask via atomicOr).
__global__ void __launch_bounds__(256) k_rank(const float* __restrict__ scores,
                                              u32* __restrict__ partial,
                                              u64* __restrict__ nbrw) {
  __shared__ u64 kj[256];
  int tid = threadIdx.x;
  int j = blockIdx.y * 256 + tid;
  kj[tid] = sort_key(scores[j], j);
  __syncthreads();
  int i = blockIdx.x * 256 + tid;
  if (blockIdx.y == 0) nbrw[i] = 0;
  u64 ki = sort_key(scores[i], i);
  int cnt = 0;
  #pragma unroll 16
  for (int t = 0; t < 256; ++t) cnt += (kj[t] < ki) ? 1 : 0;   // LDS broadcast
  partial[i * 16 + blockIdx.y] = (u32)cnt;
}

// ---------- K1b: sum partials -> rank; scatter gather + BEV into sorted order.
__global__ void __launch_bounds__(256) k_scatter(const u32* __restrict__ partial,
                                                 const float* __restrict__ scores,
                                                 const float* __restrict__ boxes9,
                                                 const int* __restrict__ labels,
                                                 float* __restrict__ box9s, float4* __restrict__ bevs,
                                                 float* __restrict__ scoress, int* __restrict__ labelss) {
  #pragma clang fp contract(off)
  int i = blockIdx.x * 256 + threadIdx.x;
  const uint4* p4 = (const uint4*)(partial + i * 16);
  uint4 a0 = p4[0], a1 = p4[1], a2 = p4[2], a3 = p4[3];
  int r = (int)(a0.x + a0.y + a0.z + a0.w + a1.x + a1.y + a1.z + a1.w +
                a2.x + a2.y + a2.z + a2.w + a3.x + a3.y + a3.z + a3.w);
  float b[9];
  #pragma unroll
  for (int f = 0; f < 9; ++f) b[f] = boxes9[i * 9 + f];
  #pragma unroll
  for (int f = 0; f < 9; ++f) box9s[r * 9 + f] = b[f];
  float ang = b[6] - floorf(b[6] / PI_F + 0.5f) * PI_F;
  bool sw = fabsf(ang) >= PI4_F;
  float dx = sw ? b[4] : b[3];
  float dy = sw ? b[3] : b[4];
  bevs[r] = make_float4(b[0] - dx * 0.5f, b[1] - dy * 0.5f,
                        b[0] + dx * 0.5f, b[1] + dy * 0.5f);
  scoress[r] = scores[i];
  labelss[r] = labels[i];
}

// ---------- K2: pairwise over-matrix (symmetric), bit-packed rows.
// Fused nbrw update: word jt of row i holds an earlier valid neighbor =>
// atomicOr bit jt into nbrw[i] (rare; avg ~0.5 set words per box).
__global__ void __launch_bounds__(64) k_mask(const float4* __restrict__ bevs,
                                             const int* __restrict__ labelss,
                                             const float* __restrict__ scoress,
                                             u64* __restrict__ mask,
                                             u64* __restrict__ nbrw) {
  #pragma clang fp contract(off)
  __shared__ float4 bj[64];
  __shared__ int lj[64];
  int t = threadIdx.x;
  int jt = blockIdx.x;
  int it = blockIdx.y;
  int j = jt * 64 + t;
  bj[t] = bevs[j];
  lj[t] = labelss[j];
  u64 vj = __ballot(scoress[j] > COND_THRES);   // valid mask of this j-tile
  int i = it * 64 + t;
  float4 a = bevs[i];
  int la = labelss[i];
  float area_a = (a.z - a.x) * (a.w - a.y);
  __syncthreads();
  u64 w = 0;
  #pragma unroll 8
  for (int kk = 0; kk < 64; ++kk) {
    float4 bb = bj[kk];
    float xmin = fmaxf(a.x, bb.x), ymin = fmaxf(a.y, bb.y);
    float xmax = fminf(a.z, bb.z), ymax = fminf(a.w, bb.w);
    float inter = fmaxf(xmax - xmin, 0.0f) * fmaxf(ymax - ymin, 0.0f);
    float area_b = (bb.z - bb.x) * (bb.w - bb.y);
    float iou = inter / fmaxf(area_a + area_b - inter, 1e-6f);
    if ((iou > IOU_THRES) && (la == lj[kk])) w |= (1ull << kk);
  }
  mask[(u64)i * NW + jt] = w;
  if (jt <= it) {
    u64 below = (jt < it) ? ~0ull : ((1ull << t) - 1ull);
    if (w & vj & below) atomicOr(&nbrw[i], 1ull << jt);
  }
}

// ---------- K3: greedy NMS fixpoint; neighbor words register-cached so rounds
// are pure LDS/VALU (global mask touched only in init + rare >2-word fallback).
__global__ void __launch_bounds__(1024) k_nms(const u64* __restrict__ mask,
                                              const u64* __restrict__ nbrw,
                                              const float* __restrict__ scoress,
                                              u64* __restrict__ keptOut) {
  __shared__ u64 decided[64], kept[64];
  __shared__ int remaining;
  int tid = threadIdx.x;
  if (tid < 64) {
    u64 v = 0;
    #pragma unroll 8
    for (int b = 0; b < 64; ++b)
      if (scoress[(tid << 6) | b] > COND_THRES) v |= (1ull << b);
    decided[tid] = ~v;       // invalid boxes decided (kept=0) from the start
    kept[tid] = 0;
  }
  if (tid == 0) remaining = 0;
  __syncthreads();
  if (tid < 64) atomicAdd(&remaining, __popcll(~decided[tid]));
  // register cache: up to 2 masked neighbor words per owned box
  u64 cw0[4], cw1[4];
  u32 meta[4];   // [5:0] idx0, [11:6] idx1, [13:12] n(min 2), [14] overflow
  #pragma unroll
  for (int s = 0; s < 4; ++s) {
    int i = tid + (s << 10);
    int wi = i >> 6;
    u64 bit = 1ull << (i & 63);
    u64 t = nbrw[i];
    int n = 0; u32 ovf = 0;
    u64 c0 = 0, c1 = 0; u32 i0 = 0, i1 = 0;
    while (t) {
      int w = __builtin_ctzll(t);
      t &= t - 1;
      u64 below = (w < wi) ? ~0ull : (bit - 1ull);
      u64 m = mask[(u64)i * NW + w] & below;
      if (n == 0)      { c0 = m; i0 = (u32)w; }
      else if (n == 1) { c1 = m; i1 = (u32)w; }
      else ovf = 1;
      ++n;
    }
    cw0[s] = c0; cw1[s] = c1;
    meta[s] = i0 | (i1 << 6) | ((u32)(n > 2 ? 2 : n) << 12) | (ovf << 14);
  }
  __syncthreads();
  while (remaining > 0) {
    int decIdx[4]; bool decKept[4]; int nDec = 0;
    #pragma unroll
    for (int s = 0; s < 4; ++s) {
      int i = tid + (s << 10);
      int wi = i >> 6;
      u64 bit = 1ull << (i & 63);
      if (decided[wi] & bit) continue;
      bool hasU = false, hasK = false;
      u32 mt = meta[s];
      if (!(mt & (1u << 14))) {
        int n = (mt >> 12) & 3;
        if (n >= 1) {
          int w = mt & 63;
          hasU = hasU || ((cw0[s] & ~decided[w]) != 0ull);
          hasK = hasK || ((cw0[s] & kept[w]) != 0ull);
        }
        if (n >= 2) {
          int w = (mt >> 6) & 63;
          hasU = hasU || ((cw1[s] & ~decided[w]) != 0ull);
          hasK = hasK || ((cw1[s] & kept[w]) != 0ull);
        }
      } else {
        u64 t = nbrw[i];
        while (t) {
          int w = __builtin_ctzll(t);
          t &= t - 1;
          u64 below = (w < wi) ? ~0ull : (bit - 1ull);
          u64 m = mask[(u64)i * NW + w] & below;
          hasU = hasU || ((m & ~decided[w]) != 0ull);
          hasK = hasK || ((m & kept[w]) != 0ull);
        }
      }
      if (!hasU) { decIdx[nDec] = i; decKept[nDec] = !hasK; ++nDec; }
    }
    __syncthreads();
    for (int d = 0; d < nDec; ++d) {
      int i = decIdx[d];
      u64 bit = 1ull << (i & 63);
      atomicOr(&decided[i >> 6], bit);
      if (decKept[d]) atomicOr(&kept[i >> 6], bit);
      atomicSub(&remaining, 1);
    }
    __syncthreads();
  }
  if (tid < 64) keptOut[tid] = kept[tid];
}

// ---------- K4: supstep[j] = min{i kept : over(i,j)} (parallel), -1 if invalid.
__global__ void __launch_bounds__(256) k_supstep(const u64* __restrict__ mask,
                                                 const u64* __restrict__ kept,
                                                 const float* __restrict__ scoress,
                                                 int* __restrict__ supstep) {
  __shared__ u64 K[64];
  if (threadIdx.x < 64) K[threadIdx.x] = kept[threadIdx.x];
  __syncthreads();
  int j = blockIdx.x * 256 + threadIdx.x;
  if (!(scoress[j] > COND_THRES)) { supstep[j] = -1; return; }
  int res = 0x7FFFFFFF;
  #pragma unroll 4
  for (int w = 0; w < 64; ++w) {
    u64 m = mask[(u64)j * NW + w] & K[w];
    if (m) { res = (w << 6) + __builtin_ctzll(m); break; }
  }
  supstep[j] = res;
}

// ---------- K5: per-box merge + all outputs. One 64-thread block per sorted box.
__global__ void __launch_bounds__(64) k_merge(
    const u64* __restrict__ mask, const int* __restrict__ supstep,
    const float* __restrict__ box9s, const float* __restrict__ scoress,
    const int* __restrict__ labelss,
    const float* __restrict__ w1, const float* __restrict__ b1,
    const float* __restrict__ w2, const float* __restrict__ b2,
    const float* __restrict__ w3, const float* __restrict__ b3,
    float* __restrict__ out) {
  #pragma clang fp contract(off)
  __shared__ int candList[MM];
  __shared__ float ob[MM][7];
  __shared__ float h1[7][HH];
  __shared__ float h2[7][HH];
  __shared__ float res[7];
  int i = blockIdx.x;
  int t = threadIdx.x;
  bool active = (supstep[i] == i);
  u64 wq = 0;
  int cnt = 0;
  if (active) {
    u64 w = mask[(u64)i * NW + t];
    while (w) {
      int b = __builtin_ctzll(w);
      w &= w - 1;
      int j = (t << 6) | b;
      if (supstep[j] >= i) { wq |= (1ull << b); cnt++; }
    }
  }
  int incl = cnt;
  #pragma unroll
  for (int off = 1; off < 64; off <<= 1) {
    int v = __shfl_up(incl, off);
    if (t >= off) incl += v;
  }
  int excl = incl - cnt;
  int count = __shfl(incl, 63);
  bool merged = active && (count > 1);
  if (merged && wq) {
    int pos = excl;
    u64 ww = wq;
    while (ww && pos < MM) {
      int b = __builtin_ctzll(ww);
      ww &= ww - 1;
      candList[pos++] = (t << 6) | b;
    }
  }
  __syncthreads();
  if (merged) {
    int nc = count < MM ? count : MM;
    if (t < MM) {
      if (t < nc) {
        int j = candList[t];
        #pragma unroll
        for (int f = 0; f < 7; ++f) ob[t][f] = box9s[j * 9 + f];
      } else {
        #pragma unroll
        for (int f = 0; f < 7; ++f) ob[t][f] = 0.0f;
      }
    }
    __syncthreads();
    for (int o = t; o < 7 * HH; o += 64) {
      int f = o >> 4, hh = o & 15;
      float acc = b1[hh];
      #pragma unroll
      for (int m = 0; m < MM; ++m) acc += ob[m][f] * w1[m * HH + hh];
      h1[f][hh] = fmaxf(acc, 0.0f);
    }
    __syncthreads();
    for (int o = t; o < 7 * HH; o += 64) {
      int f = o >> 4, oo = o & 15;
      float acc = b2[oo];
      #pragma unroll
      for (int k = 0; k < HH; ++k) acc += h1[f][k] * w2[k * HH + oo];
      h2[f][oo] = fmaxf(acc, 0.0f);
    }
    __syncthreads();
    if (t < 7) {
      float acc = b3[0];
      #pragma unroll
      for (int k = 0; k < HH; ++k) acc += h2[t][k] * w3[k];
      if (t >= 3 && t < 6) acc = fmaxf(acc, 1e-5f);
      res[t] = acc;
    }
    __syncthreads();
  }
  if (t < 9) {
    float v = box9s[i * 9 + t];
    if (merged && t < 7) v = res[t];
    out[i * 9 + t] = v;
  }
  if (t == 0) {
    out[NB * 9 + i]          = scoress[i];
    out[NB * 9 + NB + i]     = (float)labelss[i];
    out[NB * 9 + 2 * NB + i] = active ? 1.0f : 0.0f;
  }
}

extern "C" void kernel_launch(void* const* d_in, const int* in_sizes, int n_in,
                              void* d_out, int out_size, void* d_ws, size_t ws_size,
                              hipStream_t stream) {
  const float* boxes9 = (const float*)d_in[0];
  const float* scores = (const float*)d_in[1];
  const int*   labels = (const int*)d_in[2];
  const float* w1 = (const float*)d_in[3];
  const float* b1 = (const float*)d_in[4];
  const float* w2 = (const float*)d_in[5];
  const float* b2 = (const float*)d_in[6];
  const float* w3 = (const float*)d_in[7];
  const float* b3 = (const float*)d_in[8];
  char* ws = (char*)d_ws;
  u64*    kept    = (u64*)(ws + WS_KEPT);
  u64*    mask    = (u64*)(ws + WS_MASK);
  float*  box9s   = (float*)(ws + WS_BOX9S);
  float4* bevs    = (float4*)(ws + WS_BEVS);
  float*  scoress = (float*)(ws + WS_SCORES);
  int*    labelss = (int*)(ws + WS_LABELS);
  int*    supstep = (int*)(ws + WS_SUPSTEP);
  u64*    nbrw    = (u64*)(ws + WS_NBRW);
  u32*    part    = (u32*)(ws + WS_PART);
  float*  out     = (float*)d_out;

  hipLaunchKernelGGL(k_rank,    dim3(16, 16),   dim3(256),  0, stream, scores, part, nbrw);
  hipLaunchKernelGGL(k_scatter, dim3(NB / 256), dim3(256),  0, stream, part, scores, boxes9, labels,
                     box9s, bevs, scoress, labelss);
  hipLaunchKernelGGL(k_mask,    dim3(64, 64),   dim3(64),   0, stream, bevs, labelss, scoress,
                     mask, nbrw);
  hipLaunchKernelGGL(k_nms,     dim3(1),        dim3(1024), 0, stream, mask, nbrw, scoress, kept);
  hipLaunchKernelGGL(k_supstep, dim3(NB / 256), dim3(256),  0, stream, mask, kept, scoress, supstep);
  hipLaunchKernelGGL(k_merge,   dim3(NB),       dim3(64),   0, stream, mask, supstep,
                     box9s, scoress, labelss, w1, b1, w2, b2, w3, b3, out);
}